// Round 3
// baseline (6524.905 us; speedup 1.0000x reference)
//
#include <hip/hip_runtime.h>

typedef unsigned short u16;
typedef __attribute__((ext_vector_type(8))) short bf16x8;
typedef __attribute__((ext_vector_type(4))) float f32x4;

__device__ __forceinline__ float bf2f(u16 u) { return __uint_as_float(((unsigned)u) << 16); }
__device__ __forceinline__ u16 f2bf(float f) {
  unsigned u = __float_as_uint(f);
  u += 0x7fffu + ((u >> 16) & 1u);   // RNE
  return (u16)(u >> 16);
}
// order-preserving float->uint encoding for atomicMax (init 0 == "below -inf")
__device__ __forceinline__ unsigned fenc(float f) {
  unsigned u = __float_as_uint(f);
  return (u & 0x80000000u) ? ~u : (u | 0x80000000u);
}
__device__ __forceinline__ float fdec(unsigned u) {
  return (u & 0x80000000u) ? __uint_as_float(u & 0x7fffffffu) : __uint_as_float(~u);
}

// ---------------------------------------------------------------------------
// Split f32 -> (hi, lo) bf16 pairs, packed: [x | Wl1 | Wr1 | Wl2 | Wr2 | Wjk]
// ---------------------------------------------------------------------------
__global__ __launch_bounds__(256) void split6_kernel(
    const float* __restrict__ x,  const float* __restrict__ w0,
    const float* __restrict__ w1, const float* __restrict__ w2,
    const float* __restrict__ w3, const float* __restrict__ w4,
    u16* __restrict__ HI, u16* __restrict__ LO, int nx, int total)
{
  int i = blockIdx.x * 256 + threadIdx.x;
  if (i >= total) return;
  const float* src; int j = i;
  if (j < nx) src = x;
  else { j -= nx;
    if (j < 65536) src = w0;
    else { j -= 65536;
      if (j < 65536) src = w1;
      else { j -= 65536;
        if (j < 131072) src = w2;
        else { j -= 131072;
          if (j < 131072) src = w3;
          else { j -= 131072; src = w4; } } } } }
  float v = src[j];
  u16 h = f2bf(v);
  HI[i] = h;
  LO[i] = f2bf(v - bf2f(h));
}

// ---------------------------------------------------------------------------
// GEMM: C[M, coff:coff+Nc] (f32) = sum_{s=0..2} A_s[M,K_s] @ B_s[K_s,Nc] + bias
// 64x64 block tile, 4 waves (each 16 rows x 64 cols), mfma 16x16x32 bf16.
// B staged in LDS [64n][40 stride]; bias (f32) indexed locally by column.
// ---------------------------------------------------------------------------
__global__ __launch_bounds__(256) void gemm3_kernel(
    const u16* __restrict__ A0, int lda0, int K0,
    const u16* __restrict__ A1, int lda1, int K1,
    const u16* __restrict__ A2, int lda2, int K2,
    const u16* __restrict__ B0, const u16* __restrict__ B1, const u16* __restrict__ B2,
    int ldb,
    const float* __restrict__ bias,
    float* __restrict__ C, int ldc, int coff,
    int M)
{
  __shared__ u16 ldsB[64 * 40];
  const int tid  = threadIdx.x;
  const int lane = tid & 63;
  const int wid  = tid >> 6;
  const int quad = lane >> 4;
  const int r16  = lane & 15;
  const int m0   = blockIdx.x * 64;
  const int n0   = blockIdx.y * 64;

  f32x4 acc[4] = {{0,0,0,0},{0,0,0,0},{0,0,0,0},{0,0,0,0}};

  const u16* As[3]  = {A0, A1, A2};
  const u16* Bs[3]  = {B0, B1, B2};
  const int  Ks[3]  = {K0, K1, K2};
  const int  lds_[3] = {lda0, lda1, lda2};

#pragma unroll
  for (int s = 0; s < 3; ++s) {
    const int K = Ks[s];
    if (K == 0) continue;
    const u16* A  = As[s];
    const u16* Bp = Bs[s];
    const int lda = lds_[s];
    int arow = m0 + wid * 16 + r16; if (arow >= M) arow = M - 1;  // masked at store
    const u16* aptr = A + (size_t)arow * lda + quad * 8;

    const int nn = tid & 63, kk = tid >> 6;
    for (int k0 = 0; k0 < K; k0 += 32) {
      __syncthreads();
#pragma unroll
      for (int r = 0; r < 8; ++r) {
        int k = kk + 4 * r;
        ldsB[nn * 40 + k] = Bp[(size_t)(k0 + k) * ldb + n0 + nn];
      }
      __syncthreads();
      bf16x8 a = *reinterpret_cast<const bf16x8*>(aptr + k0);
#pragma unroll
      for (int nc = 0; nc < 4; ++nc) {
        bf16x8 b = *reinterpret_cast<const bf16x8*>(&ldsB[(nc * 16 + r16) * 40 + quad * 8]);
        acc[nc] = __builtin_amdgcn_mfma_f32_16x16x32_bf16(a, b, acc[nc], 0, 0, 0);
      }
    }
  }

#pragma unroll
  for (int nc = 0; nc < 4; ++nc) {
    const int col = n0 + nc * 16 + r16;
    const float bv = bias ? bias[col] : 0.f;
#pragma unroll
    for (int r = 0; r < 4; ++r) {
      int m = m0 + wid * 16 + quad * 4 + r;
      if (m < M) C[(size_t)m * ldc + coff + col] = acc[nc][r] + bv;
    }
  }
}

// ---------------------------------------------------------------------------
// Edge pass A: logits[e,h] = sum_c lrelu(xl[src,h,c]+xr[dst,h,c]) * att[h,c]
// one wave per edge (grid-stride); 8 lanes per head; atomicMax encoded max.
// XLR row layout (f32): [xl(0..D-1) | xr(D..2D-1)], row stride 2D.
// ---------------------------------------------------------------------------
template<int C>
__global__ __launch_bounds__(256) void edge_logits_kernel(
    const float* __restrict__ XLR,
    const int* __restrict__ ei, int E, int ET,
    const float* __restrict__ att,
    float* __restrict__ LOG, unsigned* __restrict__ MKEY)
{
  constexpr int D = C * 8;
  constexpr int VPL = D / 64;       // floats per lane: 8 (C=64) or 4 (C=32)
  __shared__ float attS[D];
  for (int i = threadIdx.x; i < D; i += 256) attS[i] = att[i];
  __syncthreads();

  const int lane = threadIdx.x & 63;
  const int h = lane >> 3;
  const int wid = (blockIdx.x * 256 + threadIdx.x) >> 6;
  const int nw = (gridDim.x * 256) >> 6;

  for (int e = wid; e < ET; e += nw) {
    int s, d;
    if (e < E) { s = ei[e]; d = ei[E + e]; } else { s = e - E; d = s; }
    const float4* xl4 = (const float4*)(XLR + (size_t)s * (2 * D) + lane * VPL);
    const float4* xr4 = (const float4*)(XLR + (size_t)d * (2 * D) + D + lane * VPL);
    float p = 0.f;
#pragma unroll
    for (int w = 0; w < VPL / 4; ++w) {
      float4 L = xl4[w], R = xr4[w];
      float v;
      v = L.x + R.x; v = v > 0.f ? v : 0.2f * v; p += v * attS[lane * VPL + 4 * w + 0];
      v = L.y + R.y; v = v > 0.f ? v : 0.2f * v; p += v * attS[lane * VPL + 4 * w + 1];
      v = L.z + R.z; v = v > 0.f ? v : 0.2f * v; p += v * attS[lane * VPL + 4 * w + 2];
      v = L.w + R.w; v = v > 0.f ? v : 0.2f * v; p += v * attS[lane * VPL + 4 * w + 3];
    }
    p += __shfl_xor(p, 1);
    p += __shfl_xor(p, 2);
    p += __shfl_xor(p, 4);
    if ((lane & 7) == 0) {
      LOG[(size_t)e * 8 + h] = p;
      atomicMax(&MKEY[(size_t)d * 8 + h], fenc(p));
    }
  }
}

// ---------------------------------------------------------------------------
// Edge pass B: a = exp(logit - m[dst,h]); DEN[dst,h] += a; ACC[dst,:] += a*xl[src,:]
// ---------------------------------------------------------------------------
template<int C>
__global__ __launch_bounds__(256) void edge_accum_kernel(
    const float* __restrict__ XLR,
    const int* __restrict__ ei, int E, int ET,
    const float* __restrict__ LOG, const unsigned* __restrict__ MKEY,
    float* __restrict__ DEN, float* __restrict__ ACC)
{
  constexpr int D = C * 8;
  constexpr int VPL = D / 64;
  const int lane = threadIdx.x & 63;
  const int h = lane >> 3;
  const int wid = (blockIdx.x * 256 + threadIdx.x) >> 6;
  const int nw = (gridDim.x * 256) >> 6;

  for (int e = wid; e < ET; e += nw) {
    int s, d;
    if (e < E) { s = ei[e]; d = ei[E + e]; } else { s = e - E; d = s; }
    const float a = __expf(LOG[(size_t)e * 8 + h] - fdec(MKEY[(size_t)d * 8 + h]));
    if ((lane & 7) == 0) atomicAdd(&DEN[(size_t)d * 8 + h], a);
    const float4* xl4 = (const float4*)(XLR + (size_t)s * (2 * D) + lane * VPL);
    float* accp = ACC + (size_t)d * D + lane * VPL;
#pragma unroll
    for (int w = 0; w < VPL / 4; ++w) {
      float4 L = xl4[w];
      atomicAdd(&accp[4 * w + 0], a * L.x);
      atomicAdd(&accp[4 * w + 1], a * L.y);
      atomicAdd(&accp[4 * w + 2], a * L.z);
      atomicAdd(&accp[4 * w + 3], a * L.w);
    }
  }
}

// ---------------------------------------------------------------------------
// Normalize + bias + ELU; write bf16 hi (and optionally lo) for next GEMMs.
// ---------------------------------------------------------------------------
template<int C, bool WLO>
__global__ __launch_bounds__(256) void norm_elu_kernel(
    const float* __restrict__ ACC, const float* __restrict__ DEN,
    const float* __restrict__ bias,
    u16* __restrict__ Hh, u16* __restrict__ Hl, int Nn)
{
  constexpr int D = C * 8;
  const long long idx = (long long)blockIdx.x * 256 + threadIdx.x;
  if (idx >= (long long)Nn * D) return;
  const int n = (int)(idx / D);
  const int i = (int)(idx - (long long)n * D);
  const int h = i / C;
  float v = ACC[idx] / DEN[n * 8 + h] + bias[i];
  v = v > 0.f ? v : expm1f(v);
  u16 hh = f2bf(v);
  Hh[idx] = hh;
  if (WLO) Hl[idx] = f2bf(v - bf2f(hh));
}

// ---------------------------------------------------------------------------

extern "C" void kernel_launch(void* const* d_in, const int* in_sizes, int n_in,
                              void* d_out, int out_size, void* d_ws, size_t ws_size,
                              hipStream_t stream) {
  const float* x     = (const float*)d_in[0];
  const int*   ei    = (const int*)d_in[1];
  const float* Wl1   = (const float*)d_in[2];
  const float* bl1   = (const float*)d_in[3];
  const float* Wr1   = (const float*)d_in[4];
  const float* br1   = (const float*)d_in[5];
  const float* att1  = (const float*)d_in[6];
  const float* bias1 = (const float*)d_in[7];
  const float* Wl2   = (const float*)d_in[8];
  const float* bl2   = (const float*)d_in[9];
  const float* Wr2   = (const float*)d_in[10];
  const float* br2   = (const float*)d_in[11];
  const float* att2  = (const float*)d_in[12];
  const float* bias2 = (const float*)d_in[13];
  const float* Wjk   = (const float*)d_in[14];
  const float* bjk   = (const float*)d_in[15];
  float* out = (float*)d_out;

  const int Nn = in_sizes[0] / 128;   // 20000
  const int E  = in_sizes[1] / 2;     // 320000
  const int ET = E + Nn;              // 340000

  // packed split offsets (elements)
  const size_t nx    = (size_t)Nn * 128;          // 2,560,000
  const size_t oWl1  = nx;
  const size_t oWr1  = nx + 65536;
  const size_t oWl2  = nx + 131072;
  const size_t oWr2  = nx + 262144;
  const size_t oWjk  = nx + 393216;
  const size_t nsplit = nx + 507904;              // 3,067,904

  // workspace layout (bytes), ~168 MB total
  char* ws = (char*)d_ws;
  size_t off = 0;
  u16* HI = (u16*)(ws + off); off += nsplit * 2;            // 6,135,808
  u16* LO = (u16*)(ws + off); off += nsplit * 2;            // 12,271,616
  float* XLR1f = (float*)(ws + off);                        // [N][1024] f32
  float* XLR2f = XLR1f;                                     // [N][512]  (alias, after L1 edges)
  u16* H1l = (u16*)((char*)XLR1f + (size_t)Nn * 512 * 4);   // [N][512] bf16 (alias tail)
  u16* H2h = (u16*)((char*)XLR1f + (size_t)Nn * 768 * 4);   // [N][256] bf16 (alias tail)
  off += (size_t)Nn * 1024 * 4;
  u16* H1h = (u16*)(ws + off); off += (size_t)Nn * 512 * 2; // [N][512] bf16
  float* ACC = (float*)(ws + off); off += (size_t)Nn * 512 * 4;
  float* LOGb = (float*)(ws + off); off += (size_t)ET * 8 * 4;
  unsigned* MKEY = (unsigned*)(ws + off); off += (size_t)Nn * 8 * 4;
  float* DEN = (float*)(ws + off); off += (size_t)Nn * 8 * 4;

  const int mblocks = (Nn + 63) / 64;

  // ---------------- split x + weights into hi/lo bf16 ----------------
  split6_kernel<<<((int)nsplit + 255) / 256, 256, 0, stream>>>(
      x, Wl1, Wr1, Wl2, Wr2, Wjk, HI, LO, (int)nx, (int)nsplit);

  // ---------------- Layer 1 ----------------
  hipMemsetAsync(MKEY, 0, (size_t)Nn * 8 * 4, stream);
  hipMemsetAsync(DEN,  0, (size_t)Nn * 8 * 4, stream);
  hipMemsetAsync(ACC,  0, (size_t)Nn * 512 * 4, stream);

  dim3 g1(mblocks, 512 / 64);
  // xl1 = x@Wl1 (split: Ah*Bh + Ah*Bl + Al*Bh) + bl1
  gemm3_kernel<<<g1, 256, 0, stream>>>(HI, 128, 128, HI, 128, 128, LO, 128, 128,
                                       HI + oWl1, LO + oWl1, HI + oWl1, 512, bl1,
                                       XLR1f, 1024, 0, Nn);
  gemm3_kernel<<<g1, 256, 0, stream>>>(HI, 128, 128, HI, 128, 128, LO, 128, 128,
                                       HI + oWr1, LO + oWr1, HI + oWr1, 512, br1,
                                       XLR1f, 1024, 512, Nn);
  edge_logits_kernel<64><<<2048, 256, 0, stream>>>(XLR1f, ei, E, ET, att1, LOGb, MKEY);
  edge_accum_kernel<64><<<2048, 256, 0, stream>>>(XLR1f, ei, E, ET, LOGb, MKEY, DEN, ACC);
  norm_elu_kernel<64, true><<<(Nn * 512 + 255) / 256, 256, 0, stream>>>(
      ACC, DEN, bias1, H1h, H1l, Nn);

  // ---------------- Layer 2 ----------------
  hipMemsetAsync(MKEY, 0, (size_t)Nn * 8 * 4, stream);
  hipMemsetAsync(DEN,  0, (size_t)Nn * 8 * 4, stream);
  hipMemsetAsync(ACC,  0, (size_t)Nn * 256 * 4, stream);

  dim3 g2(mblocks, 256 / 64);
  gemm3_kernel<<<g2, 256, 0, stream>>>(H1h, 512, 512, H1h, 512, 512, H1l, 512, 512,
                                       HI + oWl2, LO + oWl2, HI + oWl2, 256, bl2,
                                       XLR2f, 512, 0, Nn);
  gemm3_kernel<<<g2, 256, 0, stream>>>(H1h, 512, 512, H1h, 512, 512, H1l, 512, 512,
                                       HI + oWr2, LO + oWr2, HI + oWr2, 256, br2,
                                       XLR2f, 512, 256, Nn);
  edge_logits_kernel<32><<<2048, 256, 0, stream>>>(XLR2f, ei, E, ET, att2, LOGb, MKEY);
  edge_accum_kernel<32><<<2048, 256, 0, stream>>>(XLR2f, ei, E, ET, LOGb, MKEY, DEN, ACC);
  norm_elu_kernel<32, false><<<(Nn * 256 + 255) / 256, 256, 0, stream>>>(
      ACC, DEN, bias2, H2h, nullptr, Nn);

  // ---------------- JK linear: out = [x|h1|h2] @ Wjk + bjk (hi-only) --------
  dim3 g3(mblocks, 128 / 64);
  gemm3_kernel<<<g3, 256, 0, stream>>>(HI, 128, 128, H1h, 512, 512, H2h, 256, 256,
                                       HI + oWjk, HI + oWjk + 128 * 128, HI + oWjk + 640 * 128,
                                       128, bjk,
                                       out, 128, 0, Nn);
}

// Round 4
// 579.175 us; speedup vs baseline: 11.2659x; 11.2659x over previous
//
#include <hip/hip_runtime.h>

typedef unsigned short u16;
typedef __attribute__((ext_vector_type(8))) short bf16x8;
typedef __attribute__((ext_vector_type(4))) float f32x4;

__device__ __forceinline__ float bf2f(u16 u) { return __uint_as_float(((unsigned)u) << 16); }
__device__ __forceinline__ u16 f2bf(float f) {
  unsigned u = __float_as_uint(f);
  u += 0x7fffu + ((u >> 16) & 1u);   // RNE
  return (u16)(u >> 16);
}

// ---------------------------------------------------------------------------
// Split f32 -> (hi, lo) bf16 pairs, packed: [x | Wl1 | Wr1 | Wl2 | Wr2 | Wjk]
// ---------------------------------------------------------------------------
__global__ __launch_bounds__(256) void split6_kernel(
    const float* __restrict__ x,  const float* __restrict__ w0,
    const float* __restrict__ w1, const float* __restrict__ w2,
    const float* __restrict__ w3, const float* __restrict__ w4,
    u16* __restrict__ HI, u16* __restrict__ LO, int nx, int total)
{
  int i = blockIdx.x * 256 + threadIdx.x;
  if (i >= total) return;
  const float* src; int j = i;
  if (j < nx) src = x;
  else { j -= nx;
    if (j < 65536) src = w0;
    else { j -= 65536;
      if (j < 65536) src = w1;
      else { j -= 65536;
        if (j < 131072) src = w2;
        else { j -= 131072;
          if (j < 131072) src = w3;
          else { j -= 131072; src = w4; } } } } }
  float v = src[j];
  u16 h = f2bf(v);
  HI[i] = h;
  LO[i] = f2bf(v - bf2f(h));
}

// ---------------------------------------------------------------------------
// CSR build: histogram -> exclusive scan -> scatter srcs by dst
// ---------------------------------------------------------------------------
__global__ __launch_bounds__(256) void hist_kernel(
    const int* __restrict__ ei, int E, int ET, int* __restrict__ cnt)
{
  int e = blockIdx.x * 256 + threadIdx.x;
  if (e >= ET) return;
  int d = (e < E) ? ei[E + e] : (e - E);
  atomicAdd(&cnt[d], 1);
}

__global__ __launch_bounds__(1024) void scan_kernel(
    const int* __restrict__ cnt, int* __restrict__ rowptr, int n)
{
  __shared__ int buf[1024];
  __shared__ int carry;
  if (threadIdx.x == 0) carry = 0;
  __syncthreads();
  for (int base = 0; base < n; base += 1024) {
    int i = base + threadIdx.x;
    int v = (i < n) ? cnt[i] : 0;
    buf[threadIdx.x] = v;
    __syncthreads();
    for (int ofs = 1; ofs < 1024; ofs <<= 1) {
      int t = (threadIdx.x >= ofs) ? buf[threadIdx.x - ofs] : 0;
      __syncthreads();
      buf[threadIdx.x] += t;
      __syncthreads();
    }
    int incl = buf[threadIdx.x];
    int c = carry;
    if (i < n) rowptr[i] = c + incl - v;
    int total = buf[1023];
    __syncthreads();
    if (threadIdx.x == 0) carry = c + total;
    __syncthreads();
  }
  if (threadIdx.x == 0) rowptr[n] = carry;
}

__global__ __launch_bounds__(256) void scatter_kernel(
    const int* __restrict__ ei, int E, int ET,
    const int* __restrict__ rowptr, int* __restrict__ cur, int* __restrict__ srcs)
{
  int e = blockIdx.x * 256 + threadIdx.x;
  if (e >= ET) return;
  int s, d;
  if (e < E) { s = ei[e]; d = ei[E + e]; } else { s = e - E; d = s; }
  int pos = rowptr[d] + atomicAdd(&cur[d], 1);
  srcs[pos] = s;
}

// ---------------------------------------------------------------------------
// GEMM: C[M, coff:coff+Nc] (f32) = sum_{s=0..2} A_s[M,K_s] @ B_s[K_s,Nc] + bias
// 64x64 block tile, 4 waves (each 16 rows x 64 cols), mfma 16x16x32 bf16.
// ---------------------------------------------------------------------------
__global__ __launch_bounds__(256) void gemm3_kernel(
    const u16* __restrict__ A0, int lda0, int K0,
    const u16* __restrict__ A1, int lda1, int K1,
    const u16* __restrict__ A2, int lda2, int K2,
    const u16* __restrict__ B0, const u16* __restrict__ B1, const u16* __restrict__ B2,
    int ldb,
    const float* __restrict__ bias,
    float* __restrict__ C, int ldc, int coff,
    int M)
{
  __shared__ u16 ldsB[64 * 40];
  const int tid  = threadIdx.x;
  const int lane = tid & 63;
  const int wid  = tid >> 6;
  const int quad = lane >> 4;
  const int r16  = lane & 15;
  const int m0   = blockIdx.x * 64;
  const int n0   = blockIdx.y * 64;

  f32x4 acc[4] = {{0,0,0,0},{0,0,0,0},{0,0,0,0},{0,0,0,0}};

  const u16* As[3]  = {A0, A1, A2};
  const u16* Bs[3]  = {B0, B1, B2};
  const int  Ks[3]  = {K0, K1, K2};
  const int  lds_[3] = {lda0, lda1, lda2};

#pragma unroll
  for (int s = 0; s < 3; ++s) {
    const int K = Ks[s];
    if (K == 0) continue;
    const u16* A  = As[s];
    const u16* Bp = Bs[s];
    const int lda = lds_[s];
    int arow = m0 + wid * 16 + r16; if (arow >= M) arow = M - 1;  // masked at store
    const u16* aptr = A + (size_t)arow * lda + quad * 8;

    const int nn = tid & 63, kk = tid >> 6;
    for (int k0 = 0; k0 < K; k0 += 32) {
      __syncthreads();
#pragma unroll
      for (int r = 0; r < 8; ++r) {
        int k = kk + 4 * r;
        ldsB[nn * 40 + k] = Bp[(size_t)(k0 + k) * ldb + n0 + nn];
      }
      __syncthreads();
      bf16x8 a = *reinterpret_cast<const bf16x8*>(aptr + k0);
#pragma unroll
      for (int nc = 0; nc < 4; ++nc) {
        bf16x8 b = *reinterpret_cast<const bf16x8*>(&ldsB[(nc * 16 + r16) * 40 + quad * 8]);
        acc[nc] = __builtin_amdgcn_mfma_f32_16x16x32_bf16(a, b, acc[nc], 0, 0, 0);
      }
    }
  }

#pragma unroll
  for (int nc = 0; nc < 4; ++nc) {
    const int col = n0 + nc * 16 + r16;
    const float bv = bias ? bias[col] : 0.f;
#pragma unroll
    for (int r = 0; r < 4; ++r) {
      int m = m0 + wid * 16 + quad * 4 + r;
      if (m < M) C[(size_t)m * ldc + coff + col] = acc[nc][r] + bv;
    }
  }
}

// ---------------------------------------------------------------------------
// Fused GATv2 aggregation: one wave per dst node, online softmax per head,
// register accumulation, no atomics. XLR row: [xl(0..D-1) | xr(D..2D-1)].
// Output: ELU(acc/den + bias) as bf16 hi (+ optional lo).
// Lane l holds elements [l*VPL, l*VPL+VPL); head = l/8 (8 lanes per head).
// ---------------------------------------------------------------------------
template<int C, bool WLO>
__global__ __launch_bounds__(256) void gat_node_kernel(
    const float* __restrict__ XLR,
    const int* __restrict__ rowptr, const int* __restrict__ srcs,
    const float* __restrict__ att, const float* __restrict__ bias,
    u16* __restrict__ Hh, u16* __restrict__ Hl, int Nn)
{
  constexpr int D = C * 8;
  constexpr int VPL = D / 64;          // 8 (C=64) or 4 (C=32)
  constexpr int NV4 = VPL / 4;
  const int lane = threadIdx.x & 63;
  const int wv  = (blockIdx.x * 256 + threadIdx.x) >> 6;
  const int nwv = (gridDim.x * 256) >> 6;

  float attR[VPL], biasR[VPL];
#pragma unroll
  for (int w = 0; w < VPL; ++w) {
    attR[w]  = att[lane * VPL + w];
    biasR[w] = bias[lane * VPL + w];
  }

  for (int d = wv; d < Nn; d += nwv) {
    float xrR[VPL];
    {
      const float4* p = (const float4*)(XLR + (size_t)d * (2 * D) + D + lane * VPL);
#pragma unroll
      for (int w = 0; w < NV4; ++w) { float4 t = p[w];
        xrR[4*w] = t.x; xrR[4*w+1] = t.y; xrR[4*w+2] = t.z; xrR[4*w+3] = t.w; }
    }
    const int jb = rowptr[d], je = rowptr[d + 1];
    float m = -INFINITY, den = 0.f;
    float acc[VPL];
#pragma unroll
    for (int w = 0; w < VPL; ++w) acc[w] = 0.f;

    float xlR[VPL];
    {
      const float4* p = (const float4*)(XLR + (size_t)srcs[jb] * (2 * D) + lane * VPL);
#pragma unroll
      for (int w = 0; w < NV4; ++w) { float4 t = p[w];
        xlR[4*w] = t.x; xlR[4*w+1] = t.y; xlR[4*w+2] = t.z; xlR[4*w+3] = t.w; }
    }

    for (int j = jb; j < je; ++j) {
      float xlN[VPL];
      if (j + 1 < je) {
        const float4* p = (const float4*)(XLR + (size_t)srcs[j + 1] * (2 * D) + lane * VPL);
#pragma unroll
        for (int w = 0; w < NV4; ++w) { float4 t = p[w];
          xlN[4*w] = t.x; xlN[4*w+1] = t.y; xlN[4*w+2] = t.z; xlN[4*w+3] = t.w; }
      }
      float p = 0.f;
#pragma unroll
      for (int w = 0; w < VPL; ++w) {
        float v = xlR[w] + xrR[w];
        v = v > 0.f ? v : 0.2f * v;
        p += v * attR[w];
      }
      p += __shfl_xor(p, 1);
      p += __shfl_xor(p, 2);
      p += __shfl_xor(p, 4);              // logit for this lane's head
      const float mn = fmaxf(m, p);
      const float f  = __expf(m - mn);    // m=-inf first iter -> f=0
      const float pe = __expf(p - mn);
      den = den * f + pe;
#pragma unroll
      for (int w = 0; w < VPL; ++w) acc[w] = acc[w] * f + pe * xlR[w];
      m = mn;
#pragma unroll
      for (int w = 0; w < VPL; ++w) xlR[w] = xlN[w];
    }

    const float inv = 1.f / den;
    u16* hh = Hh + (size_t)d * D + lane * VPL;
    u16* hl = WLO ? (Hl + (size_t)d * D + lane * VPL) : nullptr;
#pragma unroll
    for (int w = 0; w < VPL; ++w) {
      float v = acc[w] * inv + biasR[w];
      v = v > 0.f ? v : expm1f(v);
      u16 h = f2bf(v);
      hh[w] = h;
      if (WLO) hl[w] = f2bf(v - bf2f(h));
    }
  }
}

// ---------------------------------------------------------------------------

extern "C" void kernel_launch(void* const* d_in, const int* in_sizes, int n_in,
                              void* d_out, int out_size, void* d_ws, size_t ws_size,
                              hipStream_t stream) {
  const float* x     = (const float*)d_in[0];
  const int*   ei    = (const int*)d_in[1];
  const float* Wl1   = (const float*)d_in[2];
  const float* bl1   = (const float*)d_in[3];
  const float* Wr1   = (const float*)d_in[4];
  const float* br1   = (const float*)d_in[5];
  const float* att1  = (const float*)d_in[6];
  const float* bias1 = (const float*)d_in[7];
  const float* Wl2   = (const float*)d_in[8];
  const float* bl2   = (const float*)d_in[9];
  const float* Wr2   = (const float*)d_in[10];
  const float* br2   = (const float*)d_in[11];
  const float* att2  = (const float*)d_in[12];
  const float* bias2 = (const float*)d_in[13];
  const float* Wjk   = (const float*)d_in[14];
  const float* bjk   = (const float*)d_in[15];
  float* out = (float*)d_out;

  const int Nn = in_sizes[0] / 128;   // 20000
  const int E  = in_sizes[1] / 2;     // 320000
  const int ET = E + Nn;              // 340000

  // packed split offsets (elements)
  const size_t nx    = (size_t)Nn * 128;
  const size_t oWl1  = nx;
  const size_t oWr1  = nx + 65536;
  const size_t oWl2  = nx + 131072;
  const size_t oWr2  = nx + 262144;
  const size_t oWjk  = nx + 393216;
  const size_t nsplit = nx + 507904;

  // workspace layout (no aliasing between concurrent reader/writer regions)
  char* ws = (char*)d_ws;
  size_t off = 0;
  u16* HI = (u16*)(ws + off); off += nsplit * 2;
  u16* LO = (u16*)(ws + off); off += nsplit * 2;
  float* XLR1f = (float*)(ws + off);                 // [N][1024] f32 (L1)
  float* XLR2f = XLR1f;                              // [N][512]  f32 (L2, sequential reuse)
  off += (size_t)Nn * 1024 * 4;
  u16* H1h = (u16*)(ws + off); off += (size_t)Nn * 512 * 2;
  u16* H1l = (u16*)(ws + off); off += (size_t)Nn * 512 * 2;
  u16* H2h = (u16*)(ws + off); off += (size_t)Nn * 256 * 2;
  int* rowptr = (int*)(ws + off); off += (size_t)(Nn + 1) * 4;
  int* cur    = (int*)(ws + off); off += (size_t)Nn * 4;
  int* srcs   = (int*)(ws + off); off += (size_t)ET * 4;

  const int mblocks = (Nn + 63) / 64;
  const int nodeblocks = (Nn + 3) / 4;   // 1 wave per node, 4 waves/block

  // ---------------- split + CSR build ----------------
  split6_kernel<<<((int)nsplit + 255) / 256, 256, 0, stream>>>(
      x, Wl1, Wr1, Wl2, Wr2, Wjk, HI, LO, (int)nx, (int)nsplit);
  hipMemsetAsync(cur, 0, (size_t)Nn * 4, stream);
  hist_kernel<<<(ET + 255) / 256, 256, 0, stream>>>(ei, E, ET, cur);
  scan_kernel<<<1, 1024, 0, stream>>>(cur, rowptr, Nn);
  hipMemsetAsync(cur, 0, (size_t)Nn * 4, stream);
  scatter_kernel<<<(ET + 255) / 256, 256, 0, stream>>>(ei, E, ET, rowptr, cur, srcs);

  // ---------------- Layer 1 ----------------
  dim3 g1(mblocks, 512 / 64);
  gemm3_kernel<<<g1, 256, 0, stream>>>(HI, 128, 128, HI, 128, 128, LO, 128, 128,
                                       HI + oWl1, LO + oWl1, HI + oWl1, 512, bl1,
                                       XLR1f, 1024, 0, Nn);
  gemm3_kernel<<<g1, 256, 0, stream>>>(HI, 128, 128, HI, 128, 128, LO, 128, 128,
                                       HI + oWr1, LO + oWr1, HI + oWr1, 512, br1,
                                       XLR1f, 1024, 512, Nn);
  gat_node_kernel<64, true><<<nodeblocks, 256, 0, stream>>>(
      XLR1f, rowptr, srcs, att1, bias1, H1h, H1l, Nn);

  // ---------------- Layer 2 ----------------
  dim3 g2(mblocks, 256 / 64);
  gemm3_kernel<<<g2, 256, 0, stream>>>(H1h, 512, 512, H1h, 512, 512, H1l, 512, 512,
                                       HI + oWl2, LO + oWl2, HI + oWl2, 256, bl2,
                                       XLR2f, 512, 0, Nn);
  gemm3_kernel<<<g2, 256, 0, stream>>>(H1h, 512, 512, H1h, 512, 512, H1l, 512, 512,
                                       HI + oWr2, LO + oWr2, HI + oWr2, 256, br2,
                                       XLR2f, 512, 256, Nn);
  gat_node_kernel<32, false><<<nodeblocks, 256, 0, stream>>>(
      XLR2f, rowptr, srcs, att2, bias2, H2h, nullptr, Nn);

  // ---------------- JK linear: out = [x|h1|h2] @ Wjk + bjk (hi-only) --------
  dim3 g3(mblocks, 128 / 64);
  gemm3_kernel<<<g3, 256, 0, stream>>>(HI, 128, 128, H1h, 512, 512, H2h, 256, 256,
                                       HI + oWjk, HI + oWjk + 128 * 128, HI + oWjk + 640 * 128,
                                       128, bjk,
                                       out, 128, 0, Nn);
}